// Round 1
// baseline (607.925 us; speedup 1.0000x reference)
//
#include <hip/hip_runtime.h>

// LSTM: HIDDEN=128, SEQ=7, BATCH=65536. fp32 in/out.
// Strategy: split-fp16 3-pass MFMA GEMM per timestep (fp32-accurate),
// batch-tiled 64 rows/block, c/h state in registers, h staged via LDS.

#define SEQ 7
#define BT 64

typedef _Float16 half8 __attribute__((ext_vector_type(8)));
typedef float floatx4 __attribute__((ext_vector_type(4)));

__device__ __forceinline__ floatx4 mfma16(half8 a, half8 b, floatx4 c) {
  return __builtin_amdgcn_mfma_f32_16x16x32_f16(a, b, c, 0, 0, 0);
}

__device__ __forceinline__ float fsig(float v) {
  float e = __expf(-v);
  return __builtin_amdgcn_rcpf(1.0f + e);
}
__device__ __forceinline__ float ftanh(float v) {
  float e = __expf(-2.0f * v);
  return 2.0f * __builtin_amdgcn_rcpf(1.0f + e) - 1.0f;
}

// Pack W_hh [512][128] fp32 into fragment-major fp16 hi/lo arrays.
// B-operand layout for mfma_f32_16x16x32_f16: lane = kq*16 + col holds
// B[k = kq*8 + jj][n = col] for the 16-col tile. Fragment-major so each
// wave's frag load is global_load_dwordx4, fully coalesced.
__global__ void pack_kernel(const float* __restrict__ Whh,
                            _Float16* __restrict__ Bp) {
  int idx = blockIdx.x * 256 + threadIdx.x;   // 0..65535 = j*128 + k
  float wv = Whh[idx];
  _Float16 hi = (_Float16)wv;
  _Float16 lo = (_Float16)(wv - (float)hi);
  int j = idx >> 7, k = idx & 127;
  int nt = j >> 4, col = j & 15;              // 16-col N-tile, col within
  int kk = k >> 5, r = k & 31;                // 32-K step, k within
  int kq = r >> 3, jj = r & 7;
  int base = (((nt << 2) + kk) * 64 + (kq << 4) + col) * 8 + jj;
  Bp[base] = hi;
  Bp[65536 + base] = lo;
}

__launch_bounds__(256, 2)
__global__ void lstm_kernel(const float* __restrict__ x,
                            const float* __restrict__ x0,
                            const float* __restrict__ Wih,
                            const float* __restrict__ bih,
                            const float* __restrict__ bhh,
                            const float* __restrict__ Wout,
                            const float* __restrict__ boutp,
                            const _Float16* __restrict__ Bp,
                            float* __restrict__ out) {
  // h staged as fp16 hi/lo, [row][k] with +8 pad (272B stride = 4-bank
  // rotation -> conflict-free ds_read_b128 A-fragments, 16B aligned).
  __shared__ _Float16 Ahi[64][136];
  __shared__ _Float16 Alo[64][136];
  __shared__ float xs[64];
  __shared__ float predp[4][64];

  const int tid = threadIdx.x;
  const int w = tid >> 6;          // wave 0..3: owns hc [32w, 32w+32)
  const int lane = tid & 63;
  const int col = lane & 15;
  const int quad = lane >> 4;
  const int rowbase = blockIdx.x * BT;

  // zero h state in LDS (h0 = 0)
  {
    unsigned int* a0 = (unsigned int*)&Ahi[0][0];
    unsigned int* a1 = (unsigned int*)&Alo[0][0];
    for (int i = tid; i < 64 * 136 / 2; i += 256) { a0[i] = 0u; a1[i] = 0u; }
  }

  // per-lane constants: gate col j = g*128 + w*32 + s*16 + col (fixed per lane)
  float wih_r[4][2], bias_r[4][2];
#pragma unroll
  for (int g = 0; g < 4; ++g)
#pragma unroll
    for (int s = 0; s < 2; ++s) {
      int j = g * 128 + w * 32 + s * 16 + col;
      wih_r[g][s] = Wih[j];
      bias_r[g][s] = bih[j] + bhh[j];
    }
  float wout_r[2];
  wout_r[0] = Wout[w * 32 + col];
  wout_r[1] = Wout[w * 32 + 16 + col];
  const float bout = boutp[0];

  float c_r[4][2][4];  // [mt][s][reg] cell state, fp32, in registers
#pragma unroll
  for (int mt = 0; mt < 4; ++mt)
#pragma unroll
    for (int s = 0; s < 2; ++s)
#pragma unroll
      for (int r = 0; r < 4; ++r) c_r[mt][s][r] = 0.f;

  float hn0[4][4];  // s=0 h_new held in regs until safe to stage
  float pp[4][4];   // pred partial

  const _Float16* BpLo = Bp + 65536;

#pragma unroll 1
  for (int t = 0; t < SEQ; ++t) {
    if (tid < BT) {
      int b = rowbase + tid;
      xs[tid] = (t == 0) ? x0[b] : x[b * 7 + (t - 1)];
    }
    __syncthreads();  // barrier A: xs + staged h ready

#pragma unroll
    for (int s = 0; s < 2; ++s) {
      floatx4 acc[4][4];  // [mt][g]
#pragma unroll
      for (int mt = 0; mt < 4; ++mt)
#pragma unroll
        for (int g = 0; g < 4; ++g)
          acc[mt][g] = (floatx4){0.f, 0.f, 0.f, 0.f};

#pragma unroll
      for (int kk = 0; kk < 4; ++kk) {
        half8 ahi[4], alo[4];
        const int k0 = kk * 32 + quad * 8;
#pragma unroll
        for (int mt = 0; mt < 4; ++mt) {
          const int row = mt * 16 + col;  // A: m = lane&15 within tile
          ahi[mt] = *(const half8*)&Ahi[row][k0];
          alo[mt] = *(const half8*)&Alo[row][k0];
        }
#pragma unroll
        for (int g = 0; g < 4; ++g) {
          const int nt = g * 8 + w * 2 + s;
          const int off = ((nt * 4 + kk) * 64 + lane) * 8;
          half8 bhi = *(const half8*)(Bp + off);
          half8 blo = *(const half8*)(BpLo + off);
#pragma unroll
          for (int mt = 0; mt < 4; ++mt) {
            acc[mt][g] = mfma16(ahi[mt], bhi, acc[mt][g]);  // hi*hi
            acc[mt][g] = mfma16(alo[mt], bhi, acc[mt][g]);  // lo*hi
            acc[mt][g] = mfma16(ahi[mt], blo, acc[mt][g]);  // hi*lo
          }
        }
      }

      // all MFMA reads of staged h (both s phases read all of A) must
      // finish in every wave before anyone overwrites it:
      if (s == 1) __syncthreads();  // barrier B

#pragma unroll
      for (int mt = 0; mt < 4; ++mt) {
#pragma unroll
        for (int r = 0; r < 4; ++r) {
          const int b_loc = mt * 16 + quad * 4 + r;  // C row
          const float xv = xs[b_loc];
          float G0 = acc[mt][0][r] + (xv * wih_r[0][s] + bias_r[0][s]);
          float G1 = acc[mt][1][r] + (xv * wih_r[1][s] + bias_r[1][s]);
          float G2 = acc[mt][2][r] + (xv * wih_r[2][s] + bias_r[2][s]);
          float G3 = acc[mt][3][r] + (xv * wih_r[3][s] + bias_r[3][s]);
          float ig = fsig(G0);
          float fg = fsig(G1);
          float gg = ftanh(G2);
          float og = fsig(G3);
          float cn = fg * c_r[mt][s][r] + ig * gg;
          c_r[mt][s][r] = cn;
          float hn = og * ftanh(cn);
          if (s == 0) {
            hn0[mt][r] = hn;
            pp[mt][r] = hn * wout_r[0];
          } else {
            pp[mt][r] += hn * wout_r[1];
            // stage h_new (hi/lo fp16) for next timestep
            float h0 = hn0[mt][r];
            _Float16 h0h = (_Float16)h0;
            _Float16 h0l = (_Float16)(h0 - (float)h0h);
            _Float16 h1h = (_Float16)hn;
            _Float16 h1l = (_Float16)(hn - (float)h1h);
            const int hc0 = w * 32 + col;
            Ahi[b_loc][hc0] = h0h;
            Alo[b_loc][hc0] = h0l;
            Ahi[b_loc][hc0 + 16] = h1h;
            Alo[b_loc][hc0 + 16] = h1l;
            // reduce pred over the 16 cols this wave holds for this row
            float v = pp[mt][r];
            v += __shfl_xor(v, 1, 64);
            v += __shfl_xor(v, 2, 64);
            v += __shfl_xor(v, 4, 64);
            v += __shfl_xor(v, 8, 64);
            if (col == 0) predp[w][b_loc] = v;
          }
        }
      }
    }
    __syncthreads();  // barrier C: staging + predp complete
    if (tid < BT) {
      float p = predp[0][tid] + predp[1][tid] + predp[2][tid] +
                predp[3][tid] + bout;
      out[(size_t)(rowbase + tid) * 7 + t] = p;
    }
  }
}

extern "C" void kernel_launch(void* const* d_in, const int* in_sizes, int n_in,
                              void* d_out, int out_size, void* d_ws, size_t ws_size,
                              hipStream_t stream) {
  const float* x    = (const float*)d_in[0];
  const float* x0   = (const float*)d_in[1];
  const float* Wih  = (const float*)d_in[2];
  const float* Whh  = (const float*)d_in[3];
  const float* bih  = (const float*)d_in[4];
  const float* bhh  = (const float*)d_in[5];
  const float* Wout = (const float*)d_in[6];
  const float* bout = (const float*)d_in[7];
  float* out = (float*)d_out;
  _Float16* Bp = (_Float16*)d_ws;  // 256 KB: [hi 128KB][lo 128KB], repacked every launch

  pack_kernel<<<256, 256, 0, stream>>>(Whh, Bp);
  lstm_kernel<<<65536 / BT, 256, 0, stream>>>(x, x0, Wih, bih, bhh, Wout, bout,
                                              Bp, out);
}

// Round 2
// 333.823 us; speedup vs baseline: 1.8211x; 1.8211x over previous
//
#include <hip/hip_runtime.h>

// LSTM: HIDDEN=128, SEQ=7, BATCH=65536. fp32 in/out.
// Strategy: split-fp16 3-pass MFMA GEMM per timestep (fp32-accurate),
// batch-tiled 64 rows/block, c/h state in registers, h staged via LDS.
//
// R2: __launch_bounds__(256,1) — R1's (256,2) capped VGPRs at 128 and
// spilled ~1.4 GB/dispatch to scratch (FETCH 962MB/WRITE 503MB observed).
// Live state needs ~190 VGPRs; (256,1) lets it allocate spill-free while
// keeping 2 waves/SIMD (<=256 VGPRs) -> 2 blocks/CU.

#define SEQ 7
#define BT 64

typedef _Float16 half8 __attribute__((ext_vector_type(8)));
typedef float floatx4 __attribute__((ext_vector_type(4)));

__device__ __forceinline__ floatx4 mfma16(half8 a, half8 b, floatx4 c) {
  return __builtin_amdgcn_mfma_f32_16x16x32_f16(a, b, c, 0, 0, 0);
}

__device__ __forceinline__ float fsig(float v) {
  float e = __expf(-v);
  return __builtin_amdgcn_rcpf(1.0f + e);
}
__device__ __forceinline__ float ftanh(float v) {
  float e = __expf(-2.0f * v);
  return 2.0f * __builtin_amdgcn_rcpf(1.0f + e) - 1.0f;
}

// Pack W_hh [512][128] fp32 into fragment-major fp16 hi/lo arrays.
// B-operand layout for mfma_f32_16x16x32_f16: lane = kq*16 + col holds
// B[k = kq*8 + jj][n = col] for the 16-col tile. Fragment-major so each
// wave's frag load is global_load_dwordx4, fully coalesced.
__global__ void pack_kernel(const float* __restrict__ Whh,
                            _Float16* __restrict__ Bp) {
  int idx = blockIdx.x * 256 + threadIdx.x;   // 0..65535 = j*128 + k
  float wv = Whh[idx];
  _Float16 hi = (_Float16)wv;
  _Float16 lo = (_Float16)(wv - (float)hi);
  int j = idx >> 7, k = idx & 127;
  int nt = j >> 4, col = j & 15;              // 16-col N-tile, col within
  int kk = k >> 5, r = k & 31;                // 32-K step, k within
  int kq = r >> 3, jj = r & 7;
  int base = (((nt << 2) + kk) * 64 + (kq << 4) + col) * 8 + jj;
  Bp[base] = hi;
  Bp[65536 + base] = lo;
}

__launch_bounds__(256, 1)
__global__ void lstm_kernel(const float* __restrict__ x,
                            const float* __restrict__ x0,
                            const float* __restrict__ Wih,
                            const float* __restrict__ bih,
                            const float* __restrict__ bhh,
                            const float* __restrict__ Wout,
                            const float* __restrict__ boutp,
                            const _Float16* __restrict__ Bp,
                            float* __restrict__ out) {
  // h staged as fp16 hi/lo, [row][k] with +8 pad (272B stride = 4-bank
  // rotation -> conflict-free ds_read_b128 A-fragments, 16B aligned).
  __shared__ _Float16 Ahi[64][136];
  __shared__ _Float16 Alo[64][136];
  __shared__ float xs[64];
  __shared__ float predp[4][64];

  const int tid = threadIdx.x;
  const int w = tid >> 6;          // wave 0..3: owns hc [32w, 32w+32)
  const int lane = tid & 63;
  const int col = lane & 15;
  const int quad = lane >> 4;
  const int rowbase = blockIdx.x * BT;

  // zero h state in LDS (h0 = 0)
  {
    unsigned int* a0 = (unsigned int*)&Ahi[0][0];
    unsigned int* a1 = (unsigned int*)&Alo[0][0];
    for (int i = tid; i < 64 * 136 / 2; i += 256) { a0[i] = 0u; a1[i] = 0u; }
  }

  // per-lane constants: gate col j = g*128 + w*32 + s*16 + col (fixed per lane)
  float wih_r[4][2], bias_r[4][2];
#pragma unroll
  for (int g = 0; g < 4; ++g)
#pragma unroll
    for (int s = 0; s < 2; ++s) {
      int j = g * 128 + w * 32 + s * 16 + col;
      wih_r[g][s] = Wih[j];
      bias_r[g][s] = bih[j] + bhh[j];
    }
  float wout_r[2];
  wout_r[0] = Wout[w * 32 + col];
  wout_r[1] = Wout[w * 32 + 16 + col];
  const float bout = boutp[0];

  float c_r[4][2][4];  // [mt][s][reg] cell state, fp32, in registers
#pragma unroll
  for (int mt = 0; mt < 4; ++mt)
#pragma unroll
    for (int s = 0; s < 2; ++s)
#pragma unroll
      for (int r = 0; r < 4; ++r) c_r[mt][s][r] = 0.f;

  float hn0[4][4];  // s=0 h_new held in regs until safe to stage
  float pp[4][4];   // pred partial

  const _Float16* BpLo = Bp + 65536;

#pragma unroll 1
  for (int t = 0; t < SEQ; ++t) {
    if (tid < BT) {
      int b = rowbase + tid;
      xs[tid] = (t == 0) ? x0[b] : x[b * 7 + (t - 1)];
    }
    __syncthreads();  // barrier A: xs + staged h ready

#pragma unroll
    for (int s = 0; s < 2; ++s) {
      floatx4 acc[4][4];  // [mt][g]
#pragma unroll
      for (int mt = 0; mt < 4; ++mt)
#pragma unroll
        for (int g = 0; g < 4; ++g)
          acc[mt][g] = (floatx4){0.f, 0.f, 0.f, 0.f};

#pragma unroll
      for (int kk = 0; kk < 4; ++kk) {
        half8 ahi[4], alo[4];
        const int k0 = kk * 32 + quad * 8;
#pragma unroll
        for (int mt = 0; mt < 4; ++mt) {
          const int row = mt * 16 + col;  // A: m = lane&15 within tile
          ahi[mt] = *(const half8*)&Ahi[row][k0];
          alo[mt] = *(const half8*)&Alo[row][k0];
        }
#pragma unroll
        for (int g = 0; g < 4; ++g) {
          const int nt = g * 8 + w * 2 + s;
          const int off = ((nt * 4 + kk) * 64 + lane) * 8;
          half8 bhi = *(const half8*)(Bp + off);
          half8 blo = *(const half8*)(BpLo + off);
#pragma unroll
          for (int mt = 0; mt < 4; ++mt) {
            acc[mt][g] = mfma16(ahi[mt], bhi, acc[mt][g]);  // hi*hi
            acc[mt][g] = mfma16(alo[mt], bhi, acc[mt][g]);  // lo*hi
            acc[mt][g] = mfma16(ahi[mt], blo, acc[mt][g]);  // hi*lo
          }
        }
      }

      // all MFMA reads of staged h (both s phases read all of A) must
      // finish in every wave before anyone overwrites it:
      if (s == 1) __syncthreads();  // barrier B

#pragma unroll
      for (int mt = 0; mt < 4; ++mt) {
#pragma unroll
        for (int r = 0; r < 4; ++r) {
          const int b_loc = mt * 16 + quad * 4 + r;  // C row
          const float xv = xs[b_loc];
          float G0 = acc[mt][0][r] + (xv * wih_r[0][s] + bias_r[0][s]);
          float G1 = acc[mt][1][r] + (xv * wih_r[1][s] + bias_r[1][s]);
          float G2 = acc[mt][2][r] + (xv * wih_r[2][s] + bias_r[2][s]);
          float G3 = acc[mt][3][r] + (xv * wih_r[3][s] + bias_r[3][s]);
          float ig = fsig(G0);
          float fg = fsig(G1);
          float gg = ftanh(G2);
          float og = fsig(G3);
          float cn = fg * c_r[mt][s][r] + ig * gg;
          c_r[mt][s][r] = cn;
          float hn = og * ftanh(cn);
          if (s == 0) {
            hn0[mt][r] = hn;
            pp[mt][r] = hn * wout_r[0];
          } else {
            pp[mt][r] += hn * wout_r[1];
            // stage h_new (hi/lo fp16) for next timestep
            float h0 = hn0[mt][r];
            _Float16 h0h = (_Float16)h0;
            _Float16 h0l = (_Float16)(h0 - (float)h0h);
            _Float16 h1h = (_Float16)hn;
            _Float16 h1l = (_Float16)(hn - (float)h1h);
            const int hc0 = w * 32 + col;
            Ahi[b_loc][hc0] = h0h;
            Alo[b_loc][hc0] = h0l;
            Ahi[b_loc][hc0 + 16] = h1h;
            Alo[b_loc][hc0 + 16] = h1l;
            // reduce pred over the 16 cols this wave holds for this row
            float v = pp[mt][r];
            v += __shfl_xor(v, 1, 64);
            v += __shfl_xor(v, 2, 64);
            v += __shfl_xor(v, 4, 64);
            v += __shfl_xor(v, 8, 64);
            if (col == 0) predp[w][b_loc] = v;
          }
        }
      }
    }
    __syncthreads();  // barrier C: staging + predp complete
    if (tid < BT) {
      float p = predp[0][tid] + predp[1][tid] + predp[2][tid] +
                predp[3][tid] + bout;
      out[(size_t)(rowbase + tid) * 7 + t] = p;
    }
  }
}

extern "C" void kernel_launch(void* const* d_in, const int* in_sizes, int n_in,
                              void* d_out, int out_size, void* d_ws, size_t ws_size,
                              hipStream_t stream) {
  const float* x    = (const float*)d_in[0];
  const float* x0   = (const float*)d_in[1];
  const float* Wih  = (const float*)d_in[2];
  const float* Whh  = (const float*)d_in[3];
  const float* bih  = (const float*)d_in[4];
  const float* bhh  = (const float*)d_in[5];
  const float* Wout = (const float*)d_in[6];
  const float* bout = (const float*)d_in[7];
  float* out = (float*)d_out;
  _Float16* Bp = (_Float16*)d_ws;  // 256 KB: [hi 128KB][lo 128KB], repacked every launch

  pack_kernel<<<256, 256, 0, stream>>>(Whh, Bp);
  lstm_kernel<<<65536 / BT, 256, 0, stream>>>(x, x0, Wih, bih, bhh, Wout, bout,
                                              Bp, out);
}

// Round 3
// 294.076 us; speedup vs baseline: 2.0672x; 1.1352x over previous
//
#include <hip/hip_runtime.h>

// LSTM: HIDDEN=128, SEQ=7, BATCH=65536. fp32 in/out.
// Strategy: split-fp16 MFMA GEMM per timestep, batch-tiled 64 rows/block,
// c/h state in registers, h staged via LDS.
//
// R2: __launch_bounds__(256,1) — (256,2) spilled ~1.4GB/dispatch. 544->297us.
// R3: 2-pass split (Ahi*Bhi + Alo*Bhi), dropping the W_lo pass. W_lo rms
//     ~1.5e-5 -> ~7e-5 gate error, well under the 1.43e-3 threshold.
//     -33% MFMA FLOPs, -50% B fragment traffic.

#define SEQ 7
#define BT 64

typedef _Float16 half8 __attribute__((ext_vector_type(8)));
typedef float floatx4 __attribute__((ext_vector_type(4)));

__device__ __forceinline__ floatx4 mfma16(half8 a, half8 b, floatx4 c) {
  return __builtin_amdgcn_mfma_f32_16x16x32_f16(a, b, c, 0, 0, 0);
}

__device__ __forceinline__ float fsig(float v) {
  float e = __expf(-v);
  return __builtin_amdgcn_rcpf(1.0f + e);
}
__device__ __forceinline__ float ftanh(float v) {
  float e = __expf(-2.0f * v);
  return 2.0f * __builtin_amdgcn_rcpf(1.0f + e) - 1.0f;
}

// Pack W_hh [512][128] fp32 into fragment-major fp16 (hi part only).
// B-operand layout for mfma_f32_16x16x32_f16: lane = kq*16 + col holds
// B[k = kq*8 + jj][n = col] for the 16-col tile. Fragment-major so each
// wave's frag load is global_load_dwordx4, fully coalesced.
__global__ void pack_kernel(const float* __restrict__ Whh,
                            _Float16* __restrict__ Bp) {
  int idx = blockIdx.x * 256 + threadIdx.x;   // 0..65535 = j*128 + k
  float wv = Whh[idx];
  _Float16 hi = (_Float16)wv;
  int j = idx >> 7, k = idx & 127;
  int nt = j >> 4, col = j & 15;              // 16-col N-tile, col within
  int kk = k >> 5, r = k & 31;                // 32-K step, k within
  int kq = r >> 3, jj = r & 7;
  int base = (((nt << 2) + kk) * 64 + (kq << 4) + col) * 8 + jj;
  Bp[base] = hi;
}

__launch_bounds__(256, 1)
__global__ void lstm_kernel(const float* __restrict__ x,
                            const float* __restrict__ x0,
                            const float* __restrict__ Wih,
                            const float* __restrict__ bih,
                            const float* __restrict__ bhh,
                            const float* __restrict__ Wout,
                            const float* __restrict__ boutp,
                            const _Float16* __restrict__ Bp,
                            float* __restrict__ out) {
  // h staged as fp16 hi/lo, [row][k] with +8 pad (272B stride = 4-bank
  // rotation -> conflict-free ds_read_b128 A-fragments, 16B aligned).
  __shared__ _Float16 Ahi[64][136];
  __shared__ _Float16 Alo[64][136];
  __shared__ float xs[64];
  __shared__ float predp[4][64];

  const int tid = threadIdx.x;
  const int w = tid >> 6;          // wave 0..3: owns hc [32w, 32w+32)
  const int lane = tid & 63;
  const int col = lane & 15;
  const int quad = lane >> 4;
  const int rowbase = blockIdx.x * BT;

  // zero h state in LDS (h0 = 0)
  {
    unsigned int* a0 = (unsigned int*)&Ahi[0][0];
    unsigned int* a1 = (unsigned int*)&Alo[0][0];
    for (int i = tid; i < 64 * 136 / 2; i += 256) { a0[i] = 0u; a1[i] = 0u; }
  }

  // per-lane constants: gate col j = g*128 + w*32 + s*16 + col (fixed per lane)
  float wih_r[4][2], bias_r[4][2];
#pragma unroll
  for (int g = 0; g < 4; ++g)
#pragma unroll
    for (int s = 0; s < 2; ++s) {
      int j = g * 128 + w * 32 + s * 16 + col;
      wih_r[g][s] = Wih[j];
      bias_r[g][s] = bih[j] + bhh[j];
    }
  float wout_r[2];
  wout_r[0] = Wout[w * 32 + col];
  wout_r[1] = Wout[w * 32 + 16 + col];
  const float bout = boutp[0];

  float c_r[4][2][4];  // [mt][s][reg] cell state, fp32, in registers
#pragma unroll
  for (int mt = 0; mt < 4; ++mt)
#pragma unroll
    for (int s = 0; s < 2; ++s)
#pragma unroll
      for (int r = 0; r < 4; ++r) c_r[mt][s][r] = 0.f;

  float hn0[4][4];  // s=0 h_new held in regs until safe to stage
  float pp[4][4];   // pred partial

#pragma unroll 1
  for (int t = 0; t < SEQ; ++t) {
    if (tid < BT) {
      int b = rowbase + tid;
      xs[tid] = (t == 0) ? x0[b] : x[b * 7 + (t - 1)];
    }
    __syncthreads();  // barrier A: xs + staged h ready

#pragma unroll
    for (int s = 0; s < 2; ++s) {
      floatx4 acc[4][4];  // [mt][g]
#pragma unroll
      for (int mt = 0; mt < 4; ++mt)
#pragma unroll
        for (int g = 0; g < 4; ++g)
          acc[mt][g] = (floatx4){0.f, 0.f, 0.f, 0.f};

#pragma unroll
      for (int kk = 0; kk < 4; ++kk) {
        half8 ahi[4], alo[4];
        const int k0 = kk * 32 + quad * 8;
#pragma unroll
        for (int mt = 0; mt < 4; ++mt) {
          const int row = mt * 16 + col;  // A: m = lane&15 within tile
          ahi[mt] = *(const half8*)&Ahi[row][k0];
          alo[mt] = *(const half8*)&Alo[row][k0];
        }
#pragma unroll
        for (int g = 0; g < 4; ++g) {
          const int nt = g * 8 + w * 2 + s;
          const int off = ((nt * 4 + kk) * 64 + lane) * 8;
          half8 bhi = *(const half8*)(Bp + off);
#pragma unroll
          for (int mt = 0; mt < 4; ++mt) {
            acc[mt][g] = mfma16(ahi[mt], bhi, acc[mt][g]);  // hi*hi
            acc[mt][g] = mfma16(alo[mt], bhi, acc[mt][g]);  // lo*hi
          }
        }
      }

      // all MFMA reads of staged h (both s phases read all of A) must
      // finish in every wave before anyone overwrites it:
      if (s == 1) __syncthreads();  // barrier B

#pragma unroll
      for (int mt = 0; mt < 4; ++mt) {
#pragma unroll
        for (int r = 0; r < 4; ++r) {
          const int b_loc = mt * 16 + quad * 4 + r;  // C row
          const float xv = xs[b_loc];
          float G0 = acc[mt][0][r] + (xv * wih_r[0][s] + bias_r[0][s]);
          float G1 = acc[mt][1][r] + (xv * wih_r[1][s] + bias_r[1][s]);
          float G2 = acc[mt][2][r] + (xv * wih_r[2][s] + bias_r[2][s]);
          float G3 = acc[mt][3][r] + (xv * wih_r[3][s] + bias_r[3][s]);
          float ig = fsig(G0);
          float fg = fsig(G1);
          float gg = ftanh(G2);
          float og = fsig(G3);
          float cn = fg * c_r[mt][s][r] + ig * gg;
          c_r[mt][s][r] = cn;
          float hn = og * ftanh(cn);
          if (s == 0) {
            hn0[mt][r] = hn;
            pp[mt][r] = hn * wout_r[0];
          } else {
            pp[mt][r] += hn * wout_r[1];
            // stage h_new (hi/lo fp16) for next timestep
            float h0 = hn0[mt][r];
            _Float16 h0h = (_Float16)h0;
            _Float16 h0l = (_Float16)(h0 - (float)h0h);
            _Float16 h1h = (_Float16)hn;
            _Float16 h1l = (_Float16)(hn - (float)h1h);
            const int hc0 = w * 32 + col;
            Ahi[b_loc][hc0] = h0h;
            Alo[b_loc][hc0] = h0l;
            Ahi[b_loc][hc0 + 16] = h1h;
            Alo[b_loc][hc0 + 16] = h1l;
            // reduce pred over the 16 cols this wave holds for this row
            float v = pp[mt][r];
            v += __shfl_xor(v, 1, 64);
            v += __shfl_xor(v, 2, 64);
            v += __shfl_xor(v, 4, 64);
            v += __shfl_xor(v, 8, 64);
            if (col == 0) predp[w][b_loc] = v;
          }
        }
      }
    }
    __syncthreads();  // barrier C: staging + predp complete
    if (tid < BT) {
      float p = predp[0][tid] + predp[1][tid] + predp[2][tid] +
                predp[3][tid] + bout;
      out[(size_t)(rowbase + tid) * 7 + t] = p;
    }
  }
}

extern "C" void kernel_launch(void* const* d_in, const int* in_sizes, int n_in,
                              void* d_out, int out_size, void* d_ws, size_t ws_size,
                              hipStream_t stream) {
  const float* x    = (const float*)d_in[0];
  const float* x0   = (const float*)d_in[1];
  const float* Wih  = (const float*)d_in[2];
  const float* Whh  = (const float*)d_in[3];
  const float* bih  = (const float*)d_in[4];
  const float* bhh  = (const float*)d_in[5];
  const float* Wout = (const float*)d_in[6];
  const float* bout = (const float*)d_in[7];
  float* out = (float*)d_out;
  _Float16* Bp = (_Float16*)d_ws;  // 128 KB fragment-major W_hh (fp16 hi)

  pack_kernel<<<256, 256, 0, stream>>>(Whh, Bp);
  lstm_kernel<<<65536 / BT, 256, 0, stream>>>(x, x0, Wih, bih, bhh, Wout, bout,
                                              Bp, out);
}